// Round 5
// baseline (350.286 us; speedup 1.0000x reference)
//
#include <hip/hip_runtime.h>

#define BB 32
#define SS 256
#define TT 256
#define HH 4096
#define EE 64

typedef unsigned int u32;

// K1: per-block (b, s-chunk, h-chunk): reduce 32 s-rows into X[1024] (LDS),
// dot with W rows 0..63 restricted to the h-chunk, atomicAdd into cond.
// cond[b,e] = (1/S) * sum_h (sum_s x[b,s,h]) * W[e,h]
// grid = 32b * 8sc * 4hc = 1024 blocks, 256 threads.
__global__ __launch_bounds__(256) void k1_cond(const float* __restrict__ x,
                                               const float* __restrict__ W,
                                               float* __restrict__ cond) {
    __shared__ float X[1024];
    int id = blockIdx.x;
    int hc = id & 3;
    int sc = (id >> 2) & 7;
    int b  = id >> 5;
    int h0 = threadIdx.x * 4;
    int hb = hc * 1024;
    const float* src = x + ((size_t)b * SS + sc * 32) * HH + hb + h0;
    float4 acc = make_float4(0.f, 0.f, 0.f, 0.f);
    for (int s = 0; s < 32; ++s) {
        float4 v = *(const float4*)(src + (size_t)s * HH);
        acc.x += v.x; acc.y += v.y; acc.z += v.z; acc.w += v.w;
    }
    *(float4*)(X + h0) = acc;
    __syncthreads();
    int wave = threadIdx.x >> 6, lane = threadIdx.x & 63;
    for (int e = wave; e < EE; e += 4) {
        const float* wrow = W + (size_t)e * HH + hb;
        float s = 0.f;
#pragma unroll
        for (int i = 0; i < 4; ++i) {
            int h = i * 256 + lane * 4;
            float4 wv = *(const float4*)(wrow + h);
            s += X[h] * wv.x + X[h + 1] * wv.y + X[h + 2] * wv.z + X[h + 3] * wv.w;
        }
#pragma unroll
        for (int off = 32; off; off >>= 1) s += __shfl_xor(s, off);
        if (lane == 0) atomicAdd(cond + b * EE + e, s * (1.0f / SS));
    }
}

// K3: H_scale = max|pb[t,e]+cond[b,e]|, d_scale = max|pd[t,e]| (e<64),
// via uint atomicMax on non-negative float bits (slots pre-zeroed).
__global__ __launch_bounds__(256) void k3_scales(const float* __restrict__ pb,
                                                 const float* __restrict__ pd,
                                                 const float* __restrict__ cond,
                                                 u32* __restrict__ scaleBits) {
    int tid = blockIdx.x * 256 + threadIdx.x;  // 32768 threads
    float hmax = 0.f, dmax = 0.f;
    for (int idx = tid; idx < BB * TT * EE; idx += 32768) {
        int e = idx & 63, t = (idx >> 6) & 255, b = idx >> 14;
        float v = pb[t * HH + e] + cond[b * EE + e];
        hmax = fmaxf(hmax, fabsf(v));
    }
    for (int idx = tid; idx < TT * EE; idx += 32768) {
        int e = idx & 63, t = idx >> 6;
        dmax = fmaxf(dmax, fabsf(pd[t * HH + e]));
    }
#pragma unroll
    for (int off = 32; off; off >>= 1) {
        hmax = fmaxf(hmax, __shfl_xor(hmax, off));
        dmax = fmaxf(dmax, __shfl_xor(dmax, off));
    }
    __shared__ float sh[4], sd[4];
    int wave = threadIdx.x >> 6, lane = threadIdx.x & 63;
    if (lane == 0) { sh[wave] = hmax; sd[wave] = dmax; }
    __syncthreads();
    if (threadIdx.x == 0) {
        float h = sh[0], d = sd[0];
#pragma unroll
        for (int i = 1; i < 4; ++i) { h = fmaxf(h, sh[i]); d = fmaxf(d, sd[i]); }
        atomicMax(scaleBits + 0, __float_as_uint(h));
        atomicMax(scaleBits + 1, __float_as_uint(d));
    }
}

// K4: one wave per (b,t) row: logits on 64 lanes -> 4x argmax (lowest-index
// tie-break, matching lax.top_k) -> 4-way softmax (== topk renorm) -> mix.
// f32 in, f32 OUT (reference returns float32).
__global__ __launch_bounds__(256) void k4_main(const float* __restrict__ pb,
                                               const float* __restrict__ pd,
                                               const float* __restrict__ limes,
                                               const float* __restrict__ shr,
                                               const float* __restrict__ gamma,
                                               const float* __restrict__ cond,
                                               const u32* __restrict__ scaleBits,
                                               float* __restrict__ out) {
    int wave = threadIdx.x >> 6, lane = threadIdx.x & 63;
    int row = blockIdx.x * 4 + wave;  // 0..8191
    int b = row >> 8, t = row & 255;

    float Hs = fmaxf(__uint_as_float(scaleBits[0]), 1e-6f);
    float Ds = fmaxf(__uint_as_float(scaleBits[1]), 1e-6f);
    float g = 1.f / (1.f + __expf(-gamma[0]));

    size_t rb = (size_t)t * HH;
    float logit = 0.5f * (pb[rb + lane] + cond[b * EE + lane]) / Hs
                + 0.5f * pd[rb + lane] / Ds;

    int selIdx[4]; float selL[4];
    float work = logit;
#pragma unroll
    for (int k = 0; k < 4; ++k) {
        float v = work; int vi = lane;
#pragma unroll
        for (int off = 32; off; off >>= 1) {
            float ov = __shfl_xor(v, off);
            int   oi = __shfl_xor(vi, off);
            if (ov > v || (ov == v && oi < vi)) { v = ov; vi = oi; }
        }
        selIdx[k] = vi; selL[k] = v;
        if (lane == vi) work = -1e30f;
    }
    float m = selL[0];
    float w0 = __expf(selL[0] - m), w1 = __expf(selL[1] - m);
    float w2 = __expf(selL[2] - m), w3 = __expf(selL[3] - m);
    float inv = 1.f / (w0 + w1 + w2 + w3);
    w0 *= inv; w1 *= inv; w2 *= inv; w3 *= inv;

    const float* L0 = limes + (size_t)selIdx[0] * HH;
    const float* L1 = limes + (size_t)selIdx[1] * HH;
    const float* L2 = limes + (size_t)selIdx[2] * HH;
    const float* L3 = limes + (size_t)selIdx[3] * HH;
    size_t ob = (size_t)row * HH;
    float one_m_g = 1.f - g;

    for (int i = 0; i < 16; ++i) {
        int h = i * 256 + lane * 4;
        float4 fb = *(const float4*)(pb + rb + h);
        float4 fd = *(const float4*)(pd + rb + h);
        float4 f0 = *(const float4*)(L0 + h);
        float4 f1 = *(const float4*)(L1 + h);
        float4 f2 = *(const float4*)(L2 + h);
        float4 f3 = *(const float4*)(L3 + h);
        float4 fs = *(const float4*)(shr + h);
        float4 r;
        float pm;
        pm = w0 * f0.x + w1 * f1.x + w2 * f2.x + w3 * f3.x;
        r.x = (fb.x + fd.x) * (one_m_g * pm + g * fs.x);
        pm = w0 * f0.y + w1 * f1.y + w2 * f2.y + w3 * f3.y;
        r.y = (fb.y + fd.y) * (one_m_g * pm + g * fs.y);
        pm = w0 * f0.z + w1 * f1.z + w2 * f2.z + w3 * f3.z;
        r.z = (fb.z + fd.z) * (one_m_g * pm + g * fs.z);
        pm = w0 * f0.w + w1 * f1.w + w2 * f2.w + w3 * f3.w;
        r.w = (fb.w + fd.w) * (one_m_g * pm + g * fs.w);
        *(float4*)(out + ob + h) = r;
    }
}

extern "C" void kernel_launch(void* const* d_in, const int* in_sizes, int n_in,
                              void* d_out, int out_size, void* d_ws, size_t ws_size,
                              hipStream_t stream) {
    // Pointers by size (proven equivalent to dict order in R2/R3 A/B).
    const float *x = 0, *pb = 0, *pd = 0, *limes = 0, *shr = 0, *gm = 0, *W = 0;
    for (int i = 0; i < n_in; ++i) {
        const float* p = (const float*)d_in[i];
        switch (in_sizes[i]) {
            case BB * SS * HH: x = p; break;
            case TT * HH: if (!pb) pb = p; else pd = p; break;
            case EE * HH: limes = p; break;
            case HH: shr = p; break;
            case 1: gm = p; break;
            case HH * HH: W = p; break;
        }
    }
    float* out = (float*)d_out;  // reference output dtype = float32

    // ws: [0..1]=scaleBits, [2..]=cond (B*E f32)
    u32* scaleBits = (u32*)d_ws;
    float* cond = (float*)d_ws + 2;

    hipMemsetAsync(d_ws, 0, (2 + BB * EE) * sizeof(float), stream);
    k1_cond<<<BB * 8 * 4, 256, 0, stream>>>(x, W, cond);
    k3_scales<<<128, 256, 0, stream>>>(pb, pd, cond, scaleBits);
    k4_main<<<BB * TT / 4, 256, 0, stream>>>(pb, pd, limes, shr, gm, cond,
                                             scaleBits, out);
}